// Round 9
// baseline (1176.827 us; speedup 1.0000x reference)
//
#include <hip/hip_runtime.h>
#include <cstdint>
#include <cstddef>

// ---------------------------------------------------------------------------
// RPN pipeline, fp64-accurate (ordering-critical: top-k rank + NMS decisions).
// fp32 inputs; all reductions accumulate in double (fp32*fp32 exact in f64).
// ---------------------------------------------------------------------------

typedef unsigned long long ull;
typedef double d4 __attribute__((ext_vector_type(4)));

#define NANCH 9
#define NPIX  2500      // 50*50
#define CIN   512
#define COUT  512
#define KTOT  4608      // 512*9
#define KSEG  2304      // KTOT/2
#define NBOX  22500     // 2500*9
#define TOPK1 10000
#define TOPK2 2000
#define WORDS 157       // ceil(10000/64)

// ---------------- conv 3x3 as implicit-im2col GEMM, f64 MFMA ---------------
// R8 post-mortem: MFMA-busy == DP floor but pipe idle 56% -> latency-bound
// (2.5 coupled 4-wave blocks/CU). Restructure: 64-thread single-wave blocks,
// 32x32 tile each, grid 79x16x2 = 2528 blocks (~10 independent waves/CU,
// fully resident, balanced). Barriers are single-wave (~free). LDS holds f32
// (cvt after ds_read) at stride 48 -> 2-way-only bank aliasing (free, m136).
// Double-buffered staging + 2-chunk-ahead global prefetch as in R8.
// C/D register->(row,col) mapping is NOT assumed: one probe MFMA with
// injective values (D[m][n] = (m+1) + 1000*(n+1), exact in f64) is decoded
// per lane (R6 failed on a guessed layout; probe verified since R7).
__global__ __launch_bounds__(64) void conv_gemm(const float* __restrict__ feat,
                                                const float* __restrict__ w,
                                                double* __restrict__ part) {
  const int p0  = blockIdx.x * 32;
  const int co0 = blockIdx.y * 32;
  const int z   = blockIdx.z;
  const int kseg0 = z * KSEG;
  __shared__ float As[2][16][48];   // [buf][k][p]  f32, stride 48 (16q+l16 banks)
  __shared__ float Bs[2][16][48];   // [buf][k][co] f32
  const int tid  = threadIdx.x;     // 0..63 == lane
  const int quad = tid >> 4;
  const int l16  = tid & 15;
  const int pl   = tid & 31;        // staging p / co column
  const int kh   = tid >> 5;        // 0..1 staging k-half
  const int pB = p0 + pl;
  const int py = pB / 50, px = pB - py * 50;

  // ---- layout probe: learn the C/D register->(m,n) mapping ----
  int pmap[4];
  {
    double av_p = (quad == 0) ? (double)(l16 + 1) : (quad == 1 ? 1.0 : 0.0);
    double bv_p = (quad == 0) ? 1.0 : (quad == 1 ? (double)(1000 * (l16 + 1)) : 0.0);
    d4 dp = (d4){0.0, 0.0, 0.0, 0.0};
    dp = __builtin_amdgcn_mfma_f64_16x16x4f64(av_p, bv_p, dp, 0, 0, 0);
#pragma unroll
    for (int r = 0; r < 4; ++r) {
      int iv = (int)(dp[r] + 0.5);
      int mm = iv % 1000 - 1;   // p-id within the 16 block
      int nn = iv / 1000 - 1;   // co-id within the 16 block
      pmap[r] = (mm & 255) | (nn << 8);
    }
  }

  d4 acc[2][2];
#pragma unroll
  for (int i = 0; i < 2; ++i)
#pragma unroll
    for (int j = 0; j < 2; ++j) acc[i][j] = (d4){0.0, 0.0, 0.0, 0.0};

  const float* wrow = w + (size_t)(co0 + pl) * KTOT + kseg0 + kh * 8;
  const int NCH = KSEG / 16;   // 144 chunks

  float wv[8], fv[8];
  // ---- load chunk 0 into regs ----
  {
    float4 t0 = *(const float4*)(wrow);
    float4 t1 = *(const float4*)(wrow + 4);
    wv[0] = t0.x; wv[1] = t0.y; wv[2] = t0.z; wv[3] = t0.w;
    wv[4] = t1.x; wv[5] = t1.y; wv[6] = t1.z; wv[7] = t1.w;
#pragma unroll
    for (int jj = 0; jj < 8; ++jj) {
      int k = kseg0 + kh * 8 + jj;
      int ci = k / 9, r = k - ci * 9, ky = r / 3, kx = r - ky * 3;
      int yy = py + ky - 1, xx = px + kx - 1;
      float v = 0.0f;
      if (pB < NPIX && yy >= 0 && yy < 50 && xx >= 0 && xx < 50)
        v = feat[ci * NPIX + yy * 50 + xx];
      fv[jj] = v;
    }
  }
  // ---- stage chunk 0 into buf 0 ----
#pragma unroll
  for (int jj = 0; jj < 8; ++jj) {
    As[0][kh * 8 + jj][pl] = fv[jj];
    Bs[0][kh * 8 + jj][pl] = wv[jj];
  }
  // ---- prefetch chunk 1 into regs ----
  if (NCH > 1) {
    float4 t0 = *(const float4*)(wrow + 16);
    float4 t1 = *(const float4*)(wrow + 20);
    wv[0] = t0.x; wv[1] = t0.y; wv[2] = t0.z; wv[3] = t0.w;
    wv[4] = t1.x; wv[5] = t1.y; wv[6] = t1.z; wv[7] = t1.w;
#pragma unroll
    for (int jj = 0; jj < 8; ++jj) {
      int k = kseg0 + 16 + kh * 8 + jj;
      int ci = k / 9, r = k - ci * 9, ky = r / 3, kx = r - ky * 3;
      int yy = py + ky - 1, xx = px + kx - 1;
      float v = 0.0f;
      if (pB < NPIX && yy >= 0 && yy < 50 && xx >= 0 && xx < 50)
        v = feat[ci * NPIX + yy * 50 + xx];
      fv[jj] = v;
    }
  }
  __syncthreads();

  for (int c = 0; c < NCH; ++c) {
    const int buf = c & 1;
    // stage chunk c+1 into the other buffer (regs loaded last iteration)
    if (c + 1 < NCH) {
#pragma unroll
      for (int jj = 0; jj < 8; ++jj) {
        As[buf ^ 1][kh * 8 + jj][pl] = fv[jj];
        Bs[buf ^ 1][kh * 8 + jj][pl] = wv[jj];
      }
    }
    // issue global loads for chunk c+2 (retire during the MFMA burst)
    if (c + 2 < NCH) {
      float4 t0 = *(const float4*)(wrow + (c + 2) * 16);
      float4 t1 = *(const float4*)(wrow + (c + 2) * 16 + 4);
      wv[0] = t0.x; wv[1] = t0.y; wv[2] = t0.z; wv[3] = t0.w;
      wv[4] = t1.x; wv[5] = t1.y; wv[6] = t1.z; wv[7] = t1.w;
#pragma unroll
      for (int jj = 0; jj < 8; ++jj) {
        int k = kseg0 + (c + 2) * 16 + kh * 8 + jj;
        int ci = k / 9, r = k - ci * 9, ky = r / 3, kx = r - ky * 3;
        int yy = py + ky - 1, xx = px + kx - 1;
        float v = 0.0f;
        if (pB < NPIX && yy >= 0 && yy < 50 && xx >= 0 && xx < 50)
          v = feat[ci * NPIX + yy * 50 + xx];
        fv[jj] = v;
      }
    }
    // MFMA burst from buf: 4 k-steps x 4 tile-MFMAs
#pragma unroll
    for (int kk = 0; kk < 16; kk += 4) {
      double av0 = (double)As[buf][kk + quad][l16];
      double av1 = (double)As[buf][kk + quad][16 + l16];
      double bv0 = (double)Bs[buf][kk + quad][l16];
      double bv1 = (double)Bs[buf][kk + quad][16 + l16];
      acc[0][0] = __builtin_amdgcn_mfma_f64_16x16x4f64(av0, bv0, acc[0][0], 0, 0, 0);
      acc[0][1] = __builtin_amdgcn_mfma_f64_16x16x4f64(av0, bv1, acc[0][1], 0, 0, 0);
      acc[1][0] = __builtin_amdgcn_mfma_f64_16x16x4f64(av1, bv0, acc[1][0], 0, 0, 0);
      acc[1][1] = __builtin_amdgcn_mfma_f64_16x16x4f64(av1, bv1, acc[1][1], 0, 0, 0);
    }
    __syncthreads();  // single-wave barrier (cheap): orders buf^1 writes/reads
  }
  // epilogue: probe-decoded scatter. Element r of acc[ti][tj] holds the
  // product for p = p0+ti*16+pm, co = co0+tj*16+pn.
  double* basez = part + (size_t)z * COUT * NPIX;
#pragma unroll
  for (int ti = 0; ti < 2; ++ti)
#pragma unroll
    for (int tj = 0; tj < 2; ++tj) {
#pragma unroll
      for (int r = 0; r < 4; ++r) {
        int mm = pmap[r] & 255, nn = pmap[r] >> 8;
        int p  = p0 + ti * 16 + mm;
        int co = co0 + tj * 16 + nn;
        if (p < NPIX) basez[(size_t)co * NPIX + p] = acc[ti][tj][r];
      }
    }
}

// ---------------- heads: relu(conv)+bias, cls+box 1x1 convs, decode --------
__global__ __launch_bounds__(256) void heads_kernel(
    const double* __restrict__ part, const float* __restrict__ rpn_b,
    const float* __restrict__ cls_w, const float* __restrict__ cls_b,
    const float* __restrict__ box_w, const float* __restrict__ box_b,
    double* __restrict__ logits, double* __restrict__ boxesAll,
    float* __restrict__ out_cls) {
  int p = blockIdx.x * blockDim.x + threadIdx.x;
  bool act = p < NPIX;
  int pp = act ? p : 0;
  double accC[9];
  double accB[36];
#pragma unroll
  for (int a = 0; a < 9; ++a) accC[a] = 0.0;
#pragma unroll
  for (int c = 0; c < 36; ++c) accB[c] = 0.0;
  const double* part1 = part + (size_t)COUT * NPIX;
  for (int co = 0; co < CIN; ++co) {
    double v = part[(size_t)co * NPIX + pp] + part1[(size_t)co * NPIX + pp] +
               (double)rpn_b[co];
    v = v > 0.0 ? v : 0.0;
#pragma unroll
    for (int a = 0; a < 9; ++a) accC[a] += (double)cls_w[a * CIN + co] * v;
#pragma unroll
    for (int c = 0; c < 36; ++c) accB[c] += (double)box_w[c * CIN + co] * v;
  }
  if (!act) return;
  int y = p / 50, x = p - y * 50;
  double sx = 16.0 * (double)x, sy = 16.0 * (double)y;
  const double scs[3] = {128.0, 256.0, 512.0};
  const double ars[3] = {0.5, 1.0, 2.0};
#pragma unroll
  for (int a = 0; a < 9; ++a) {
    double ar = ars[a / 3], sc = scs[a - (a / 3) * 3];
    double hr = sqrt(ar), wr = 1.0 / hr;
    double wv = wr * sc, hv = hr * sc;
    // jnp.round == round-half-even == rint under default rounding mode
    double bx0 = rint(-wv * 0.5), by0 = rint(-hv * 0.5);
    double bx1 = rint(wv * 0.5), by1 = rint(hv * 0.5);
    double a0 = sx + bx0, a1 = sy + by0, a2 = sx + bx1, a3 = sy + by1;
    double wA = a2 - a0, hA = a3 - a1;
    double cx = a0 + 0.5 * wA, cy = a1 + 0.5 * hA;
    double dx = accB[a * 4 + 0] + (double)box_b[a * 4 + 0];
    double dy = accB[a * 4 + 1] + (double)box_b[a * 4 + 1];
    double dw = accB[a * 4 + 2] + (double)box_b[a * 4 + 2];
    double dh = accB[a * 4 + 3] + (double)box_b[a * 4 + 3];
    double pcx = wA * dx + cx, pcy = hA * dy + cy;
    double pw = exp(dw) * wA, ph = exp(dh) * hA;
    double b0 = pcx - 0.5 * pw, b1 = pcy - 0.5 * ph;
    double b2 = pcx + 0.5 * pw, b3 = pcy + 0.5 * ph;
    b0 = fmin(fmax(b0, 0.0), 800.0);
    b1 = fmin(fmax(b1, 0.0), 800.0);
    b2 = fmin(fmax(b2, 0.0), 800.0);
    b3 = fmin(fmax(b3, 0.0), 800.0);
    int idx = p * 9 + a;
    boxesAll[(size_t)idx * 4 + 0] = b0;
    boxesAll[(size_t)idx * 4 + 1] = b1;
    boxesAll[(size_t)idx * 4 + 2] = b2;
    boxesAll[(size_t)idx * 4 + 3] = b3;
    double L = accC[a] + (double)cls_b[a];
    logits[idx] = L;
    out_cls[idx] = (float)L;
  }
}

// ---------------- exact stable descending rank (== jax.lax.top_k order) ---
__global__ __launch_bounds__(256) void rank_count(const double* __restrict__ logits,
                                                  int* __restrict__ ranks) {
  __shared__ double Ls[2048];
  int i = blockIdx.x * 256 + threadIdx.x;
  int j0 = blockIdx.y * 2048;
  int jn = NBOX - j0;
  if (jn > 2048) jn = 2048;
  for (int t = threadIdx.x; t < jn; t += 256) Ls[t] = logits[j0 + t];
  __syncthreads();
  if (i >= NBOX) return;
  double Li = logits[i];
  int cnt = 0;
  for (int t = 0; t < jn; ++t) {
    double Lj = Ls[t];
    int j = j0 + t;
    cnt += (Lj > Li || (Lj == Li && j < i)) ? 1 : 0;
  }
  atomicAdd(&ranks[i], cnt);
}

__global__ __launch_bounds__(256) void scatter_topk(const double* __restrict__ logits,
                                                    const double* __restrict__ boxesAll,
                                                    const int* __restrict__ ranks,
                                                    double* __restrict__ sLog,
                                                    double* __restrict__ sBox) {
  int i = blockIdx.x * 256 + threadIdx.x;
  if (i >= NBOX) return;
  int r = ranks[i];
  if (r < TOPK1) {
    sLog[r] = logits[i];
    sBox[(size_t)r * 4 + 0] = boxesAll[(size_t)i * 4 + 0];
    sBox[(size_t)r * 4 + 1] = boxesAll[(size_t)i * 4 + 1];
    sBox[(size_t)r * 4 + 2] = boxesAll[(size_t)i * 4 + 2];
    sBox[(size_t)r * 4 + 3] = boxesAll[(size_t)i * 4 + 3];
  }
}

// ---------------- pairwise IoU suppression bitmask (upper triangle) --------
// grid (157 i-tiles, 40 word-tiles), block 256 = 64 i x 4 words.
__global__ __launch_bounds__(256) void iou_mask(const double* __restrict__ sb,
                                                ull* __restrict__ mask) {
  const int it = blockIdx.x;
  const int wt = blockIdx.y;
  if (wt * 4 + 3 < it) return;  // block only needed for words >= i/64
  __shared__ double ib[64][4];
  __shared__ double jb[256][4];
  const int tid = threadIdx.x;
  {
    int ii = it * 64 + (tid >> 2);
    int d = tid & 3;
    ib[tid >> 2][d] = (ii < TOPK1) ? sb[(size_t)ii * 4 + d] : 0.0;
  }
  for (int t = tid; t < 1024; t += 256) {
    int jj = wt * 256 + (t >> 2);
    jb[t >> 2][t & 3] = (jj < TOPK1) ? sb[(size_t)jj * 4 + (t & 3)] : 0.0;
  }
  __syncthreads();
  const int il = tid & 63, wl = tid >> 6;
  const int i = it * 64 + il;
  const int word = wt * 4 + wl;
  if (i >= TOPK1 || word >= WORDS || word < (i >> 6)) return;
  const double x0 = ib[il][0], y0 = ib[il][1], x1 = ib[il][2], y1 = ib[il][3];
  const double areai = (x1 - x0) * (y1 - y0);
  ull bits = 0;
  const int jbase = word * 64;
  for (int b = 0; b < 64; ++b) {
    int j = jbase + b;
    if (j <= i || j >= TOPK1) continue;
    int jl = wl * 64 + b;
    double u0 = jb[jl][0], u1 = jb[jl][1], u2 = jb[jl][2], u3 = jb[jl][3];
    double xl = fmax(x0, u0), yt = fmax(y0, u1);
    double xr = fmin(x1, u2), yb = fmin(y1, u3);
    double iw = xr - xl, ih = yb - yt;
    iw = iw > 0.0 ? iw : 0.0;
    ih = ih > 0.0 ? ih : 0.0;
    double inter = iw * ih;
    double aj = (u2 - u0) * (u3 - u1);
    double un = areai + aj - inter;
    // reference: inter/un > 0.7 (0/0 -> NaN -> false). Multiply form matches.
    if (inter > 0.7 * un) bits |= 1ull << b;
  }
  mask[(size_t)i * WORDS + word] = bits;
}

// ---------------- tiled greedy-NMS scan, LDS-resident tile -----------------
#define NTILE 8
#define TRS   10    // padded ull stride for tileRows (8 words + 2 pad)
#define KCAP  2112

__global__ __launch_bounds__(256) void nms_scan(const ull* __restrict__ mask,
                                                ull* __restrict__ keepwords) {
  __shared__ ull tileRows[512 * TRS];        // 40,960 B
  __shared__ int klist[KCAP];                // kept global indices (rank order)
  __shared__ ull remvPart[32][NTILE + 1];    // column-OR partials
  __shared__ unsigned int remv32[NTILE * 2]; // removal words (lo/hi pairs)
  __shared__ int newk[64];                   // this group's kept local rows
  __shared__ int kcLds, nkLds, doneLds;
  const int tid = threadIdx.x;
  const int lane = tid & 63;
  const int wave = tid >> 6;
  if (tid == 0) { kcLds = 0; nkLds = 0; doneLds = 0; }
  __syncthreads();

  for (int T = 0; T < (WORDS + NTILE - 1) / NTILE; ++T) {
    const int G0 = T * NTILE;
    const int TW = (WORDS - G0 < NTILE) ? (WORDS - G0) : NTILE;
    const int kc0 = kcLds;
    // ---- Phase A1: stage tile rows (512 x TW words) into LDS ----
#pragma unroll
    for (int pass = 0; pass < 8; ++pass) {
      int lr = pass * 64 + (tid >> 2);   // local row 0..511
      int w  = (tid & 3) * 2;            // word pair
      int gr = G0 * 64 + lr;             // global row
      ull v0 = 0, v1 = 0;
      if (gr < TOPK1) {
        const ull* row = mask + (size_t)gr * WORDS + G0;
        if (w < TW)     v0 = row[w];
        if (w + 1 < TW) v1 = row[w + 1];
      }
      tileRows[lr * TRS + w]     = v0;
      tileRows[lr * TRS + w + 1] = v1;
    }
    // ---- Phase A2: base removal words = OR over previously-kept rows ----
    {
      int w = tid & 7, stripe = tid >> 3;   // 32 stripes x 8 words
      ull acc = 0;
      if (w < TW) {
        int t = stripe;
        for (; t + 224 < kc0; t += 256) {
          ull a0 = mask[(size_t)klist[t      ] * WORDS + G0 + w];
          ull a1 = mask[(size_t)klist[t +  32] * WORDS + G0 + w];
          ull a2 = mask[(size_t)klist[t +  64] * WORDS + G0 + w];
          ull a3 = mask[(size_t)klist[t +  96] * WORDS + G0 + w];
          ull a4 = mask[(size_t)klist[t + 128] * WORDS + G0 + w];
          ull a5 = mask[(size_t)klist[t + 160] * WORDS + G0 + w];
          ull a6 = mask[(size_t)klist[t + 192] * WORDS + G0 + w];
          ull a7 = mask[(size_t)klist[t + 224] * WORDS + G0 + w];
          acc |= ((a0 | a1) | (a2 | a3)) | ((a4 | a5) | (a6 | a7));
        }
        for (; t < kc0; t += 32) acc |= mask[(size_t)klist[t] * WORDS + G0 + w];
      }
      remvPart[stripe][w] = acc;
    }
    __syncthreads();
    if (tid < NTILE) {
      ull r = 0;
#pragma unroll
      for (int s = 0; s < 32; ++s) r |= remvPart[s][tid];
      remv32[tid * 2]     = (unsigned int)r;
      remv32[tid * 2 + 1] = (unsigned int)(r >> 32);
    }
    __syncthreads();
    // ---- Phase B: sequential resolve of the tile's groups (LDS only) ----
    for (int gi = 0; gi < TW; ++gi) {
      const int g = G0 + gi;
      if (wave == 0) {
        ull cur = ((ull)remv32[gi * 2 + 1] << 32) | remv32[gi * 2];
        unsigned int clo = __builtin_amdgcn_readfirstlane((unsigned int)cur);
        unsigned int chi = __builtin_amdgcn_readfirstlane((unsigned int)(cur >> 32));
        cur = ((ull)chi << 32) | clo;
        ull mrow = tileRows[(gi * 64 + lane) * TRS + gi];
        const unsigned int ml = (unsigned int)mrow;
        const unsigned int mh = (unsigned int)(mrow >> 32);
        const ull validm = (g == WORDS - 1) ? 0xFFFFull : ~0ull;
        ull rem = (~cur) & validm;
        while (rem) {
          int b = __ffsll((long long)rem) - 1;
          b = __builtin_amdgcn_readfirstlane(b);
          ull m = ((ull)(unsigned int)__builtin_amdgcn_readlane((int)mh, b) << 32) |
                  (unsigned int)__builtin_amdgcn_readlane((int)ml, b);
          cur |= m;
          ull above = (b == 63) ? 0ull : (~0ull << (b + 1));
          rem = (~cur) & rem & above;
        }
        ull kb = (~cur) & validm;
        if (lane == 0) keepwords[g] = kb;
        int kc = kcLds;
        if ((kb >> lane) & 1ull) {
          int ofs = __popcll(lane ? (kb & ((1ull << lane) - 1ull)) : 0ull);
          klist[kc + ofs] = g * 64 + lane;
          newk[ofs] = gi * 64 + lane;   // local row index for FU
        }
        if (lane == 0) {
          int nk = __popcll(kb);
          nkLds = nk;
          kcLds = kc + nk;
          doneLds = (kc + nk >= TOPK2) ? 1 : 0;
        }
      }
      __syncthreads();
      if (doneLds) break;
      // forward-update remaining tile words with newly kept rows (LDS only)
      if (gi + 1 < TW) {
        int w = tid & 7, k0 = tid >> 3;
        int nk = nkLds;
        if (w > gi && w < TW) {
          ull acc = 0;
          for (int kk = k0; kk < nk; kk += 32) acc |= tileRows[newk[kk] * TRS + w];
          if (acc) {
            atomicOr(&remv32[w * 2], (unsigned int)acc);
            atomicOr(&remv32[w * 2 + 1], (unsigned int)(acc >> 32));
          }
        }
      }
      __syncthreads();
    }
    if (doneLds) break;
  }
}

// ---------------- compact kept boxes, sigmoid scores, write output ---------
__global__ __launch_bounds__(256) void finalize_kernel(const ull* __restrict__ keepwords,
                                                       const double* __restrict__ sBox,
                                                       const double* __restrict__ sLog,
                                                       float* __restrict__ out) {
  __shared__ int pref[WORDS];
  int t = threadIdx.x;
  if (t == 0) {
    int s = 0;
    for (int w = 0; w < WORDS; ++w) {
      pref[w] = s;
      s += __popcll(keepwords[w]);
    }
  }
  __syncthreads();
  if (t < WORDS) {
    ull kb = keepwords[t];
    int base = pref[t];
    while (kb) {
      int b = __ffsll((long long)kb) - 1;
      kb &= kb - 1;
      if (base < TOPK2) {
        int i = t * 64 + b;
        out[base * 4 + 0] = (float)sBox[(size_t)i * 4 + 0];
        out[base * 4 + 1] = (float)sBox[(size_t)i * 4 + 1];
        out[base * 4 + 2] = (float)sBox[(size_t)i * 4 + 2];
        out[base * 4 + 3] = (float)sBox[(size_t)i * 4 + 3];
        double L = sLog[i];
        out[TOPK2 * 4 + base] = (float)(1.0 / (1.0 + exp(-L)));
      }
      ++base;
    }
  }
}

// ---------------------------------------------------------------------------
extern "C" void kernel_launch(void* const* d_in, const int* in_sizes, int n_in,
                              void* d_out, int out_size, void* d_ws, size_t ws_size,
                              hipStream_t stream) {
  // inputs: 0 image(unused) 1 feat 2 rpn_w 3 rpn_b 4 cls_w 5 cls_b 6 box_w 7 box_b
  const float* feat  = (const float*)d_in[1];
  const float* rpn_w = (const float*)d_in[2];
  const float* rpn_b = (const float*)d_in[3];
  const float* cls_w = (const float*)d_in[4];
  const float* cls_b = (const float*)d_in[5];
  const float* box_w = (const float*)d_in[6];
  const float* box_b = (const float*)d_in[7];
  float* out = (float*)d_out;

  // workspace layout (bytes, all 16B aligned); total ~34.44 MB
  char* ws = (char*)d_ws;
  double* part     = (double*)(ws);                 // 2*512*2500*8 = 20,480,000
  double* logits   = (double*)(ws + 20480000);      // 22500*8     =    180,000
  double* boxesAll = (double*)(ws + 20660000);      // 22500*4*8   =    720,000
  int*    ranks    = (int*)   (ws + 21380000);      // 22500*4     =     90,000
  double* sBox     = (double*)(ws + 21470000);      // 10000*4*8   =    320,000
  double* sLog     = (double*)(ws + 21790000);      // 10000*8     =     80,000
  ull*    mask     = (ull*)   (ws + 21870000);      // 10000*157*8 = 12,560,000
  ull*    keepw    = (ull*)   (ws + 34430000);      // 157*8       =      1,256

  hipMemsetAsync(d_out, 0, (TOPK2 * 4 + TOPK2) * sizeof(float), stream);
  hipMemsetAsync(ranks, 0, NBOX * sizeof(int), stream);
  hipMemsetAsync(keepw, 0, WORDS * sizeof(ull), stream);  // early-exit tail

  conv_gemm<<<dim3(79, 16, 2), 64, 0, stream>>>(feat, rpn_w, part);
  heads_kernel<<<10, 256, 0, stream>>>(part, rpn_b, cls_w, cls_b, box_w, box_b,
                                       logits, boxesAll, out + TOPK2 * 5);
  rank_count<<<dim3(88, 11), 256, 0, stream>>>(logits, ranks);
  scatter_topk<<<88, 256, 0, stream>>>(logits, boxesAll, ranks, sLog, sBox);
  iou_mask<<<dim3(WORDS, 40), 256, 0, stream>>>(sBox, mask);
  nms_scan<<<1, 256, 0, stream>>>(mask, keepw);
  finalize_kernel<<<1, 256, 0, stream>>>(keepw, sBox, sLog, out);
}

// Round 10
// 895.824 us; speedup vs baseline: 1.3137x; 1.3137x over previous
//
#include <hip/hip_runtime.h>
#include <cstdint>
#include <cstddef>

// ---------------------------------------------------------------------------
// RPN pipeline, fp64-accurate (ordering-critical: top-k rank + NMS decisions).
// fp32 inputs; all reductions accumulate in double (fp32*fp32 exact in f64).
// ---------------------------------------------------------------------------

typedef unsigned long long ull;
typedef double d4 __attribute__((ext_vector_type(4)));

#define NANCH 9
#define NPIX  2500      // 50*50
#define CIN   512
#define COUT  512
#define KTOT  4608      // 512*9
#define KSEG  2304      // KTOT/2
#define NBOX  22500     // 2500*9
#define TOPK1 10000
#define TOPK2 2000
#define WORDS 157       // ceil(10000/64)
#define NHEAD 45        // 9 cls + 36 box channels
#define HPAD  48        // padded per-pixel stride for head scratch

// ---------------- conv 3x3 as implicit-im2col GEMM, f64 MFMA ---------------
// R8 version (verbatim): grid (40,8,2), block 256 = 4 waves, 64x64 tile,
// double-buffered LDS, one barrier/chunk. R9's 32x32 single-wave variant
// REGRESSED (FETCH 47->73 MB, VALUBusy 40%): halved arithmetic intensity.
// C/D register->(row,col) mapping learned via a one-off probe MFMA.
__global__ __launch_bounds__(256) void conv_gemm(const float* __restrict__ feat,
                                                 const float* __restrict__ w,
                                                 double* __restrict__ part) {
  const int p0  = blockIdx.x * 64;
  const int co0 = blockIdx.y * 64;
  const int z   = blockIdx.z;
  const int kseg0 = z * KSEG;
  __shared__ double As[2][16][68];   // [buf][k][p]  f64, padded stride
  __shared__ double Bs[2][16][68];   // [buf][k][co] f64
  const int tid  = threadIdx.x;
  const int lane = tid & 63;
  const int wave = tid >> 6;
  const int quad = lane >> 4;
  const int l16  = lane & 15;
  const int wp = (wave & 1) * 32;   // wave p offset in tile
  const int wc = (wave >> 1) * 32;  // wave co offset in tile
  const int coA = tid >> 2;          // 0..63  (weight row)
  const int kA  = (tid & 3) * 4;     // 0,4,8,12
  const int plB = tid & 63;          // p local
  const int kB0 = tid >> 6;          // 0..3
  const int pB = p0 + plB;
  const int py = pB / 50, px = pB - py * 50;

  // ---- layout probe: learn the C/D register->(m,n) mapping ----
  int pmap[4];
  {
    double av_p = (quad == 0) ? (double)(l16 + 1) : (quad == 1 ? 1.0 : 0.0);
    double bv_p = (quad == 0) ? 1.0 : (quad == 1 ? (double)(1000 * (l16 + 1)) : 0.0);
    d4 dp = (d4){0.0, 0.0, 0.0, 0.0};
    dp = __builtin_amdgcn_mfma_f64_16x16x4f64(av_p, bv_p, dp, 0, 0, 0);
#pragma unroll
    for (int r = 0; r < 4; ++r) {
      int iv = (int)(dp[r] + 0.5);
      int mm = iv % 1000 - 1;   // p-id within the 16 block
      int nn = iv / 1000 - 1;   // co-id within the 16 block
      pmap[r] = (mm & 255) | (nn << 8);
    }
  }

  d4 acc[2][2];
#pragma unroll
  for (int i = 0; i < 2; ++i)
#pragma unroll
    for (int j = 0; j < 2; ++j) acc[i][j] = (d4){0.0, 0.0, 0.0, 0.0};

  const float* wbase = w + (size_t)(co0 + coA) * KTOT + kseg0 + kA;
  const int NCH = KSEG / 16;   // 144 chunks

  // ---- prologue: stage chunk 0 into buf 0; prefetch chunk 1 into regs ----
  {
    float4 wa0 = *(const float4*)(wbase);
    float fb0[4];
#pragma unroll
    for (int jj = 0; jj < 4; ++jj) {
      int k = kseg0 + kB0 + 4 * jj;
      int ci = k / 9, r = k - ci * 9, ky = r / 3, kx = r - ky * 3;
      int yy = py + ky - 1, xx = px + kx - 1;
      float v = 0.0f;
      if (pB < NPIX && yy >= 0 && yy < 50 && xx >= 0 && xx < 50)
        v = feat[ci * NPIX + yy * 50 + xx];
      fb0[jj] = v;
    }
    Bs[0][kA + 0][coA] = (double)wa0.x;
    Bs[0][kA + 1][coA] = (double)wa0.y;
    Bs[0][kA + 2][coA] = (double)wa0.z;
    Bs[0][kA + 3][coA] = (double)wa0.w;
#pragma unroll
    for (int jj = 0; jj < 4; ++jj) As[0][kB0 + 4 * jj][plB] = (double)fb0[jj];
  }
  float4 wa1 = *(const float4*)(wbase + 16);
  float fb1[4];
#pragma unroll
  for (int jj = 0; jj < 4; ++jj) {
    int k = kseg0 + 16 + kB0 + 4 * jj;
    int ci = k / 9, r = k - ci * 9, ky = r / 3, kx = r - ky * 3;
    int yy = py + ky - 1, xx = px + kx - 1;
    float v = 0.0f;
    if (pB < NPIX && yy >= 0 && yy < 50 && xx >= 0 && xx < 50)
      v = feat[ci * NPIX + yy * 50 + xx];
    fb1[jj] = v;
  }
  __syncthreads();

  for (int c = 0; c < NCH; ++c) {
    const int buf = c & 1;
    // stage chunk c+1 into the other buffer (regs loaded last iteration)
    if (c + 1 < NCH) {
      Bs[buf ^ 1][kA + 0][coA] = (double)wa1.x;
      Bs[buf ^ 1][kA + 1][coA] = (double)wa1.y;
      Bs[buf ^ 1][kA + 2][coA] = (double)wa1.z;
      Bs[buf ^ 1][kA + 3][coA] = (double)wa1.w;
#pragma unroll
      for (int jj = 0; jj < 4; ++jj)
        As[buf ^ 1][kB0 + 4 * jj][plB] = (double)fb1[jj];
    }
    // issue global loads for chunk c+2 (retire during the MFMA burst)
    if (c + 2 < NCH) {
      wa1 = *(const float4*)(wbase + (c + 2) * 16);
#pragma unroll
      for (int jj = 0; jj < 4; ++jj) {
        int k = kseg0 + (c + 2) * 16 + kB0 + 4 * jj;
        int ci = k / 9, r = k - ci * 9, ky = r / 3, kx = r - ky * 3;
        int yy = py + ky - 1, xx = px + kx - 1;
        float v = 0.0f;
        if (pB < NPIX && yy >= 0 && yy < 50 && xx >= 0 && xx < 50)
          v = feat[ci * NPIX + yy * 50 + xx];
        fb1[jj] = v;
      }
    }
    // MFMA burst from buf: 4 k-steps x 4 tile-MFMAs
#pragma unroll
    for (int kk = 0; kk < 16; kk += 4) {
      double av0 = As[buf][kk + quad][wp + l16];
      double av1 = As[buf][kk + quad][wp + 16 + l16];
      double bv0 = Bs[buf][kk + quad][wc + l16];
      double bv1 = Bs[buf][kk + quad][wc + 16 + l16];
      acc[0][0] = __builtin_amdgcn_mfma_f64_16x16x4f64(av0, bv0, acc[0][0], 0, 0, 0);
      acc[0][1] = __builtin_amdgcn_mfma_f64_16x16x4f64(av0, bv1, acc[0][1], 0, 0, 0);
      acc[1][0] = __builtin_amdgcn_mfma_f64_16x16x4f64(av1, bv0, acc[1][0], 0, 0, 0);
      acc[1][1] = __builtin_amdgcn_mfma_f64_16x16x4f64(av1, bv1, acc[1][1], 0, 0, 0);
    }
    __syncthreads();  // iter-c writes of buf^1 <-> iter-c+1 reads of buf^1
  }
  // epilogue: probe-decoded scatter
  double* basez = part + (size_t)z * COUT * NPIX;
#pragma unroll
  for (int ti = 0; ti < 2; ++ti)
#pragma unroll
    for (int tj = 0; tj < 2; ++tj) {
#pragma unroll
      for (int r = 0; r < 4; ++r) {
        int mm = pmap[r] & 255, nn = pmap[r] >> 8;
        int p  = p0 + wp + ti * 16 + mm;
        int co = co0 + wc + tj * 16 + nn;
        if (p < NPIX) basez[(size_t)co * NPIX + p] = acc[ti][tj][r];
      }
    }
}

// ---------------- heads stage 1: output-parallel 1x1-conv GEMM -------------
// Old heads_kernel was 10 blocks / 40 waves streaming 20.5 MB of f64 ->
// concurrency-bound (~300+ us). New: thread = (pixel, head-channel o).
// grid (40 pixel-tiles, 12 o-quads), block 256 = 4 waves; each wave has a
// single wave-uniform o (scalar weight loads), lanes cover 64 pixels
// (coalesced part reads). rpn bias + relu applied here; head biases in
// decode. Summation order co=0..511 ascending (same as before -> numerics
// unchanged). Writes headsc[p*48 + o] (f64).
__global__ __launch_bounds__(256) void heads_mm(
    const double* __restrict__ part, const float* __restrict__ rpn_b,
    const float* __restrict__ cls_w, const float* __restrict__ box_w,
    double* __restrict__ headsc) {
  const int lane = threadIdx.x & 63;
  const int o = __builtin_amdgcn_readfirstlane(blockIdx.y * 4 + (threadIdx.x >> 6));
  if (o >= NHEAD) return;
  const int p = blockIdx.x * 64 + lane;
  const bool act = p < NPIX;
  const int pp = act ? p : 0;
  const float* wsel = (o < 9) ? (cls_w + (size_t)o * CIN)
                              : (box_w + (size_t)(o - 9) * CIN);
  const double* p0 = part + pp;
  const double* p1 = part + (size_t)COUT * NPIX + pp;
  double acc = 0.0;
#pragma unroll 4
  for (int co = 0; co < CIN; ++co) {
    double v = p0[(size_t)co * NPIX] + p1[(size_t)co * NPIX] + (double)rpn_b[co];
    v = v > 0.0 ? v : 0.0;
    acc += (double)wsel[co] * v;
  }
  if (act) headsc[(size_t)p * HPAD + o] = acc;
}

// ---------------- heads stage 2: bias + anchor decode + clamp --------------
__global__ __launch_bounds__(256) void decode_kernel(
    const double* __restrict__ headsc, const float* __restrict__ cls_b,
    const float* __restrict__ box_b, double* __restrict__ logits,
    double* __restrict__ boxesAll, float* __restrict__ out_cls) {
  int idx = blockIdx.x * blockDim.x + threadIdx.x;
  if (idx >= NBOX) return;
  int p = idx / 9, a = idx - p * 9;
  int y = p / 50, x = p - y * 50;
  double sx = 16.0 * (double)x, sy = 16.0 * (double)y;
  const double scs[3] = {128.0, 256.0, 512.0};
  const double ars[3] = {0.5, 1.0, 2.0};
  double ar = ars[a / 3], sc = scs[a - (a / 3) * 3];
  double hr = sqrt(ar), wr = 1.0 / hr;
  double wv = wr * sc, hv = hr * sc;
  // jnp.round == round-half-even == rint under default rounding mode
  double bx0 = rint(-wv * 0.5), by0 = rint(-hv * 0.5);
  double bx1 = rint(wv * 0.5), by1 = rint(hv * 0.5);
  double a0 = sx + bx0, a1 = sy + by0, a2 = sx + bx1, a3 = sy + by1;
  double wA = a2 - a0, hA = a3 - a1;
  double cx = a0 + 0.5 * wA, cy = a1 + 0.5 * hA;
  const double* hp = headsc + (size_t)p * HPAD;
  double dx = hp[9 + a * 4 + 0] + (double)box_b[a * 4 + 0];
  double dy = hp[9 + a * 4 + 1] + (double)box_b[a * 4 + 1];
  double dw = hp[9 + a * 4 + 2] + (double)box_b[a * 4 + 2];
  double dh = hp[9 + a * 4 + 3] + (double)box_b[a * 4 + 3];
  double pcx = wA * dx + cx, pcy = hA * dy + cy;
  double pw = exp(dw) * wA, ph = exp(dh) * hA;
  double b0 = pcx - 0.5 * pw, b1 = pcy - 0.5 * ph;
  double b2 = pcx + 0.5 * pw, b3 = pcy + 0.5 * ph;
  b0 = fmin(fmax(b0, 0.0), 800.0);
  b1 = fmin(fmax(b1, 0.0), 800.0);
  b2 = fmin(fmax(b2, 0.0), 800.0);
  b3 = fmin(fmax(b3, 0.0), 800.0);
  boxesAll[(size_t)idx * 4 + 0] = b0;
  boxesAll[(size_t)idx * 4 + 1] = b1;
  boxesAll[(size_t)idx * 4 + 2] = b2;
  boxesAll[(size_t)idx * 4 + 3] = b3;
  double L = hp[a] + (double)cls_b[a];
  logits[idx] = L;
  out_cls[idx] = (float)L;
}

// ---------------- exact stable descending rank (== jax.lax.top_k order) ---
__global__ __launch_bounds__(256) void rank_count(const double* __restrict__ logits,
                                                  int* __restrict__ ranks) {
  __shared__ double Ls[2048];
  int i = blockIdx.x * 256 + threadIdx.x;
  int j0 = blockIdx.y * 2048;
  int jn = NBOX - j0;
  if (jn > 2048) jn = 2048;
  for (int t = threadIdx.x; t < jn; t += 256) Ls[t] = logits[j0 + t];
  __syncthreads();
  if (i >= NBOX) return;
  double Li = logits[i];
  int cnt = 0;
  for (int t = 0; t < jn; ++t) {
    double Lj = Ls[t];
    int j = j0 + t;
    cnt += (Lj > Li || (Lj == Li && j < i)) ? 1 : 0;
  }
  atomicAdd(&ranks[i], cnt);
}

__global__ __launch_bounds__(256) void scatter_topk(const double* __restrict__ logits,
                                                    const double* __restrict__ boxesAll,
                                                    const int* __restrict__ ranks,
                                                    double* __restrict__ sLog,
                                                    double* __restrict__ sBox) {
  int i = blockIdx.x * 256 + threadIdx.x;
  if (i >= NBOX) return;
  int r = ranks[i];
  if (r < TOPK1) {
    sLog[r] = logits[i];
    sBox[(size_t)r * 4 + 0] = boxesAll[(size_t)i * 4 + 0];
    sBox[(size_t)r * 4 + 1] = boxesAll[(size_t)i * 4 + 1];
    sBox[(size_t)r * 4 + 2] = boxesAll[(size_t)i * 4 + 2];
    sBox[(size_t)r * 4 + 3] = boxesAll[(size_t)i * 4 + 3];
  }
}

// ---------------- pairwise IoU suppression bitmask (upper triangle) --------
__global__ __launch_bounds__(256) void iou_mask(const double* __restrict__ sb,
                                                ull* __restrict__ mask) {
  const int it = blockIdx.x;
  const int wt = blockIdx.y;
  if (wt * 4 + 3 < it) return;  // block only needed for words >= i/64
  __shared__ double ib[64][4];
  __shared__ double jb[256][4];
  const int tid = threadIdx.x;
  {
    int ii = it * 64 + (tid >> 2);
    int d = tid & 3;
    ib[tid >> 2][d] = (ii < TOPK1) ? sb[(size_t)ii * 4 + d] : 0.0;
  }
  for (int t = tid; t < 1024; t += 256) {
    int jj = wt * 256 + (t >> 2);
    jb[t >> 2][t & 3] = (jj < TOPK1) ? sb[(size_t)jj * 4 + (t & 3)] : 0.0;
  }
  __syncthreads();
  const int il = tid & 63, wl = tid >> 6;
  const int i = it * 64 + il;
  const int word = wt * 4 + wl;
  if (i >= TOPK1 || word >= WORDS || word < (i >> 6)) return;
  const double x0 = ib[il][0], y0 = ib[il][1], x1 = ib[il][2], y1 = ib[il][3];
  const double areai = (x1 - x0) * (y1 - y0);
  ull bits = 0;
  const int jbase = word * 64;
  for (int b = 0; b < 64; ++b) {
    int j = jbase + b;
    if (j <= i || j >= TOPK1) continue;
    int jl = wl * 64 + b;
    double u0 = jb[jl][0], u1 = jb[jl][1], u2 = jb[jl][2], u3 = jb[jl][3];
    double xl = fmax(x0, u0), yt = fmax(y0, u1);
    double xr = fmin(x1, u2), yb = fmin(y1, u3);
    double iw = xr - xl, ih = yb - yt;
    iw = iw > 0.0 ? iw : 0.0;
    ih = ih > 0.0 ? ih : 0.0;
    double inter = iw * ih;
    double aj = (u2 - u0) * (u3 - u1);
    double un = areai + aj - inter;
    // reference: inter/un > 0.7 (0/0 -> NaN -> false). Multiply form matches.
    if (inter > 0.7 * un) bits |= 1ull << b;
  }
  mask[(size_t)i * WORDS + word] = bits;
}

// ---------------- tiled greedy-NMS scan, LDS-resident tile -----------------
#define NTILE 8
#define TRS   10    // padded ull stride for tileRows (8 words + 2 pad)
#define KCAP  2112

__global__ __launch_bounds__(256) void nms_scan(const ull* __restrict__ mask,
                                                ull* __restrict__ keepwords) {
  __shared__ ull tileRows[512 * TRS];        // 40,960 B
  __shared__ int klist[KCAP];                // kept global indices (rank order)
  __shared__ ull remvPart[32][NTILE + 1];    // column-OR partials
  __shared__ unsigned int remv32[NTILE * 2]; // removal words (lo/hi pairs)
  __shared__ int newk[64];                   // this group's kept local rows
  __shared__ int kcLds, nkLds, doneLds;
  const int tid = threadIdx.x;
  const int lane = tid & 63;
  const int wave = tid >> 6;
  if (tid == 0) { kcLds = 0; nkLds = 0; doneLds = 0; }
  __syncthreads();

  for (int T = 0; T < (WORDS + NTILE - 1) / NTILE; ++T) {
    const int G0 = T * NTILE;
    const int TW = (WORDS - G0 < NTILE) ? (WORDS - G0) : NTILE;
    const int kc0 = kcLds;
    // ---- Phase A1: stage tile rows (512 x TW words) into LDS ----
#pragma unroll
    for (int pass = 0; pass < 8; ++pass) {
      int lr = pass * 64 + (tid >> 2);   // local row 0..511
      int w  = (tid & 3) * 2;            // word pair
      int gr = G0 * 64 + lr;             // global row
      ull v0 = 0, v1 = 0;
      if (gr < TOPK1) {
        const ull* row = mask + (size_t)gr * WORDS + G0;
        if (w < TW)     v0 = row[w];
        if (w + 1 < TW) v1 = row[w + 1];
      }
      tileRows[lr * TRS + w]     = v0;
      tileRows[lr * TRS + w + 1] = v1;
    }
    // ---- Phase A2: base removal words = OR over previously-kept rows ----
    {
      int w = tid & 7, stripe = tid >> 3;   // 32 stripes x 8 words
      ull acc = 0;
      if (w < TW) {
        int t = stripe;
        for (; t + 224 < kc0; t += 256) {
          ull a0 = mask[(size_t)klist[t      ] * WORDS + G0 + w];
          ull a1 = mask[(size_t)klist[t +  32] * WORDS + G0 + w];
          ull a2 = mask[(size_t)klist[t +  64] * WORDS + G0 + w];
          ull a3 = mask[(size_t)klist[t +  96] * WORDS + G0 + w];
          ull a4 = mask[(size_t)klist[t + 128] * WORDS + G0 + w];
          ull a5 = mask[(size_t)klist[t + 160] * WORDS + G0 + w];
          ull a6 = mask[(size_t)klist[t + 192] * WORDS + G0 + w];
          ull a7 = mask[(size_t)klist[t + 224] * WORDS + G0 + w];
          acc |= ((a0 | a1) | (a2 | a3)) | ((a4 | a5) | (a6 | a7));
        }
        for (; t < kc0; t += 32) acc |= mask[(size_t)klist[t] * WORDS + G0 + w];
      }
      remvPart[stripe][w] = acc;
    }
    __syncthreads();
    if (tid < NTILE) {
      ull r = 0;
#pragma unroll
      for (int s = 0; s < 32; ++s) r |= remvPart[s][tid];
      remv32[tid * 2]     = (unsigned int)r;
      remv32[tid * 2 + 1] = (unsigned int)(r >> 32);
    }
    __syncthreads();
    // ---- Phase B: sequential resolve of the tile's groups (LDS only) ----
    for (int gi = 0; gi < TW; ++gi) {
      const int g = G0 + gi;
      if (wave == 0) {
        ull cur = ((ull)remv32[gi * 2 + 1] << 32) | remv32[gi * 2];
        unsigned int clo = __builtin_amdgcn_readfirstlane((unsigned int)cur);
        unsigned int chi = __builtin_amdgcn_readfirstlane((unsigned int)(cur >> 32));
        cur = ((ull)chi << 32) | clo;
        ull mrow = tileRows[(gi * 64 + lane) * TRS + gi];
        const unsigned int ml = (unsigned int)mrow;
        const unsigned int mh = (unsigned int)(mrow >> 32);
        const ull validm = (g == WORDS - 1) ? 0xFFFFull : ~0ull;
        ull rem = (~cur) & validm;
        while (rem) {
          int b = __ffsll((long long)rem) - 1;
          b = __builtin_amdgcn_readfirstlane(b);
          ull m = ((ull)(unsigned int)__builtin_amdgcn_readlane((int)mh, b) << 32) |
                  (unsigned int)__builtin_amdgcn_readlane((int)ml, b);
          cur |= m;
          ull above = (b == 63) ? 0ull : (~0ull << (b + 1));
          rem = (~cur) & rem & above;
        }
        ull kb = (~cur) & validm;
        if (lane == 0) keepwords[g] = kb;
        int kc = kcLds;
        if ((kb >> lane) & 1ull) {
          int ofs = __popcll(lane ? (kb & ((1ull << lane) - 1ull)) : 0ull);
          klist[kc + ofs] = g * 64 + lane;
          newk[ofs] = gi * 64 + lane;   // local row index for FU
        }
        if (lane == 0) {
          int nk = __popcll(kb);
          nkLds = nk;
          kcLds = kc + nk;
          doneLds = (kc + nk >= TOPK2) ? 1 : 0;
        }
      }
      __syncthreads();
      if (doneLds) break;
      // forward-update remaining tile words with newly kept rows (LDS only)
      if (gi + 1 < TW) {
        int w = tid & 7, k0 = tid >> 3;
        int nk = nkLds;
        if (w > gi && w < TW) {
          ull acc = 0;
          for (int kk = k0; kk < nk; kk += 32) acc |= tileRows[newk[kk] * TRS + w];
          if (acc) {
            atomicOr(&remv32[w * 2], (unsigned int)acc);
            atomicOr(&remv32[w * 2 + 1], (unsigned int)(acc >> 32));
          }
        }
      }
      __syncthreads();
    }
    if (doneLds) break;
  }
}

// ---------------- compact kept boxes, sigmoid scores, write output ---------
__global__ __launch_bounds__(256) void finalize_kernel(const ull* __restrict__ keepwords,
                                                       const double* __restrict__ sBox,
                                                       const double* __restrict__ sLog,
                                                       float* __restrict__ out) {
  __shared__ int pref[WORDS];
  int t = threadIdx.x;
  if (t == 0) {
    int s = 0;
    for (int w = 0; w < WORDS; ++w) {
      pref[w] = s;
      s += __popcll(keepwords[w]);
    }
  }
  __syncthreads();
  if (t < WORDS) {
    ull kb = keepwords[t];
    int base = pref[t];
    while (kb) {
      int b = __ffsll((long long)kb) - 1;
      kb &= kb - 1;
      if (base < TOPK2) {
        int i = t * 64 + b;
        out[base * 4 + 0] = (float)sBox[(size_t)i * 4 + 0];
        out[base * 4 + 1] = (float)sBox[(size_t)i * 4 + 1];
        out[base * 4 + 2] = (float)sBox[(size_t)i * 4 + 2];
        out[base * 4 + 3] = (float)sBox[(size_t)i * 4 + 3];
        double L = sLog[i];
        out[TOPK2 * 4 + base] = (float)(1.0 / (1.0 + exp(-L)));
      }
      ++base;
    }
  }
}

// ---------------------------------------------------------------------------
extern "C" void kernel_launch(void* const* d_in, const int* in_sizes, int n_in,
                              void* d_out, int out_size, void* d_ws, size_t ws_size,
                              hipStream_t stream) {
  // inputs: 0 image(unused) 1 feat 2 rpn_w 3 rpn_b 4 cls_w 5 cls_b 6 box_w 7 box_b
  const float* feat  = (const float*)d_in[1];
  const float* rpn_w = (const float*)d_in[2];
  const float* rpn_b = (const float*)d_in[3];
  const float* cls_w = (const float*)d_in[4];
  const float* cls_b = (const float*)d_in[5];
  const float* box_w = (const float*)d_in[6];
  const float* box_b = (const float*)d_in[7];
  float* out = (float*)d_out;

  // workspace layout (bytes, all 16B aligned); total ~34.44 MB
  char* ws = (char*)d_ws;
  double* part     = (double*)(ws);                 // 2*512*2500*8 = 20,480,000
  double* logits   = (double*)(ws + 20480000);      // 22500*8     =    180,000
  double* boxesAll = (double*)(ws + 20660000);      // 22500*4*8   =    720,000
  int*    ranks    = (int*)   (ws + 21380000);      // 22500*4     =     90,000
  double* sBox     = (double*)(ws + 21470000);      // 10000*4*8   =    320,000
  double* sLog     = (double*)(ws + 21790000);      // 10000*8     =     80,000
  ull*    mask     = (ull*)   (ws + 21870000);      // 10000*157*8 = 12,560,000
  ull*    keepw    = (ull*)   (ws + 34430000);      // 157*8       =      1,256
  // head scratch (2500*48*8 = 960,000 B) overlays the mask region: it is
  // fully consumed by decode_kernel before iou_mask writes mask.
  double* headsc   = (double*)(ws + 21870000);

  hipMemsetAsync(d_out, 0, (TOPK2 * 4 + TOPK2) * sizeof(float), stream);
  hipMemsetAsync(ranks, 0, NBOX * sizeof(int), stream);
  hipMemsetAsync(keepw, 0, WORDS * sizeof(ull), stream);  // early-exit tail

  conv_gemm<<<dim3(40, 8, 2), 256, 0, stream>>>(feat, rpn_w, part);
  heads_mm<<<dim3(40, 12), 256, 0, stream>>>(part, rpn_b, cls_w, box_w, headsc);
  decode_kernel<<<88, 256, 0, stream>>>(headsc, cls_b, box_b, logits, boxesAll,
                                        out + TOPK2 * 5);
  rank_count<<<dim3(88, 11), 256, 0, stream>>>(logits, ranks);
  scatter_topk<<<88, 256, 0, stream>>>(logits, boxesAll, ranks, sLog, sBox);
  iou_mask<<<dim3(WORDS, 40), 256, 0, stream>>>(sBox, mask);
  nms_scan<<<1, 256, 0, stream>>>(mask, keepw);
  finalize_kernel<<<1, 256, 0, stream>>>(keepw, sBox, sLog, out);
}